// Round 16
// baseline (90.664 us; speedup 1.0000x reference)
//
#include <hip/hip_runtime.h>
#include <hip/hip_bf16.h>

#define NB 4
#define NN 256
#define ND 256
#define NK 1024
#define LN_NK 6.9314718055994531f   // ln(1024)

#define K1_BLOCKS 164               // 64 PPT | 64 M-rows | 4 p1 | 32 g2
#define K2_BLOCKS 1028              // 1024 Y(x)M tiles | 4 m1

typedef __bf16 bf16x8 __attribute__((ext_vector_type(8)));
typedef float f32x4 __attribute__((ext_vector_type(4)));

__device__ __forceinline__ float wave_reduce(float s) {
#pragma unroll
  for (int m = 32; m >= 1; m >>= 1) s += __shfl_xor(s, m, 64);
  return s;
}

__device__ __forceinline__ bf16x8 load_bf8_f32(const float* p) {
  const float4 a0 = *(const float4*)p;
  const float4 a1 = *(const float4*)(p + 4);
  bf16x8 r;
  r[0] = (__bf16)a0.x; r[1] = (__bf16)a0.y; r[2] = (__bf16)a0.z; r[3] = (__bf16)a0.w;
  r[4] = (__bf16)a1.x; r[5] = (__bf16)a1.y; r[6] = (__bf16)a1.z; r[7] = (__bf16)a1.w;
  return r;
}

// K1: 0..63   PPT = P @ P^T (bf16 out; R11-verified body)
//     64..127 M own-row build: block owns 4 rows of M = sum_sigma 1s 1s^T
//             (LDS-local atomics, integer-exact in f32, no global atomics/zeroing)
//     128..131 p1[d] = sum_k P[d,k]  (R11-verified)
//     132..163 g2 partials
__global__ __launch_bounds__(256) void k1_kernel(
    const float* __restrict__ P, const float* __restrict__ A,
    const int* __restrict__ edges, const int m_edge,
    const int* __restrict__ tris, const int m_tri,
    ushort* __restrict__ PPT, float* __restrict__ M,
    float* __restrict__ p1, float* __restrict__ pg2) {
  __shared__ float Mloc[4][256];
  __shared__ float sp[4];
  const int tid = threadIdx.x;
  const int lane = tid & 63;
  const int w = tid >> 6;
  const int bid = blockIdx.x;

  if (bid < 64) {
    const int m0 = (bid >> 2) * 16;
    const int n0 = (bid & 3) * 64 + w * 16;
    const int r15 = lane & 15;
    const int g4 = lane >> 4;
    f32x4 acc = {0.f, 0.f, 0.f, 0.f};
#pragma unroll
    for (int kk = 0; kk < NK; kk += 32) {
      const int kb = kk + g4 * 8;   // same (group,elem)->k map for A and B => layout-safe
      const bf16x8 af = load_bf8_f32(P + (m0 + r15) * NK + kb);
      const bf16x8 bf = load_bf8_f32(P + (n0 + r15) * NK + kb);  // B[k][col]=P[col][k]
      acc = __builtin_amdgcn_mfma_f32_16x16x32_bf16(af, bf, acc, 0, 0, 0);
    }
#pragma unroll
    for (int r = 0; r < 4; ++r) {
      const int orow = m0 + g4 * 4 + r;   // C/D: col=lane&15, row=(lane>>4)*4+r (HW-verified)
      const __bf16 vb = (__bf16)acc[r];
      PPT[orow * NN + (n0 + r15)] = __builtin_bit_cast(unsigned short, vb);
    }
  } else if (bid < 128) {
    const int r0 = (bid - 64) * 4;        // this block owns M rows [r0, r0+4)
    for (int c = tid; c < 1024; c += 256) ((float*)Mloc)[c] = 0.0f;
    __syncthreads();
    for (int e = tid; e < m_edge; e += 256) {
      const int u = edges[2 * e];
      const int v = edges[2 * e + 1];
      if ((unsigned)(u - r0) < 4u) {
        atomicAdd(&Mloc[u - r0][u], 1.0f); atomicAdd(&Mloc[u - r0][v], 1.0f);
      }
      if ((unsigned)(v - r0) < 4u) {
        atomicAdd(&Mloc[v - r0][v], 1.0f); atomicAdd(&Mloc[v - r0][u], 1.0f);
      }
    }
    for (int e = tid; e < m_tri; e += 256) {
      const int u = tris[3 * e];
      const int v = tris[3 * e + 1];
      const int x = tris[3 * e + 2];
      if ((unsigned)(u - r0) < 4u) {
        atomicAdd(&Mloc[u - r0][u], 1.0f); atomicAdd(&Mloc[u - r0][v], 1.0f);
        atomicAdd(&Mloc[u - r0][x], 1.0f);
      }
      if ((unsigned)(v - r0) < 4u) {
        atomicAdd(&Mloc[v - r0][v], 1.0f); atomicAdd(&Mloc[v - r0][u], 1.0f);
        atomicAdd(&Mloc[v - r0][x], 1.0f);
      }
      if ((unsigned)(x - r0) < 4u) {
        atomicAdd(&Mloc[x - r0][x], 1.0f); atomicAdd(&Mloc[x - r0][u], 1.0f);
        atomicAdd(&Mloc[x - r0][v], 1.0f);
      }
    }
    __syncthreads();
#pragma unroll
    for (int r = 0; r < 4; ++r) M[(r0 + r) * NN + tid] = Mloc[r][tid];
  } else if (bid < 132) {
    const int base = (bid - 128) * 64 + w * 16;
#pragma unroll
    for (int jr = 0; jr < 16; ++jr) {
      const int row = base + jr;
      const float* pr = P + row * NK + lane * 16;
      float s = 0.0f;
#pragma unroll
      for (int q = 0; q < 4; ++q) {
        const float4 v = *(const float4*)(pr + q * 4);
        s += v.x + v.y + v.z + v.w;
      }
      s = wave_reduce(s);
      if (lane == 0) p1[row] = s;
    }
  } else {
    const int gi = bid - 132;
    float s = 0.0f;
    for (int i = gi * 256 + tid; i < 65536; i += 32 * 256) {
      const float4 v = ((const float4*)A)[i];
      s += v.x * v.x + v.y * v.y + v.z * v.z + v.w * v.w;
    }
    s = wave_reduce(s);
    if (lane == 0) sp[w] = s;
    __syncthreads();
    if (tid == 0) pg2[gi] = sp[0] + sp[1] + sp[2] + sp[3];
  }
}

// K2: 0..1023  one 16x16 tile of Y_b = (g_b PPT) g_b^T, elementwise-weighted by M,
//              reduced to one scalar partial. Z strip (16x256) built inline in LDS
//              (waves split d'); Y uses 4-wave k-split + LDS reduce (sum preserves
//              the verified C/D layout; M symmetric + full coverage => transpose-immune).
//     1024..1027  m1 partials: ps[b] = sum_v M[v][v] * (g_bv . p1)  (exact f32)
__global__ __launch_bounds__(256) void k2_kernel(
    const float* __restrict__ g, const ushort* __restrict__ PPT,
    const float* __restrict__ M, const float* __restrict__ p1,
    float* __restrict__ pm, float* __restrict__ ps) {
  __shared__ ushort Zl[16][264];   // +8 bf16 pad -> 528B rows, 2-way banks (free)
  __shared__ f32x4 red[4][64];
  __shared__ float p1s[256];
  __shared__ float sp[4];
  const int tid = threadIdx.x;
  const int lane = tid & 63;
  const int w = tid >> 6;
  const int bid = blockIdx.x;

  if (bid < 1024) {
    const int b = bid >> 8;
    const int m0 = ((bid >> 4) & 15) * 16;
    const int n0 = (bid & 15) * 16;
    const int r15 = lane & 15;
    const int g4 = lane >> 4;
    const float* gb = g + ((size_t)(b << 8)) * ND;

    // --- Z phase: Z[m0..m0+16][:] = g rows @ PPT; wave w owns d' in [w*64, w*64+64)
    bf16x8 afr[8];
#pragma unroll
    for (int ki = 0; ki < 8; ++ki)
      afr[ki] = load_bf8_f32(gb + (m0 + r15) * ND + ki * 32 + g4 * 8);
#pragma unroll
    for (int nt = 0; nt < 4; ++nt) {
      const int bcol = w * 64 + nt * 16 + r15;   // PPT row (symmetric -> row read)
      f32x4 z = {0.f, 0.f, 0.f, 0.f};
#pragma unroll
      for (int ki = 0; ki < 8; ++ki) {
        const bf16x8 bf = *(const bf16x8*)(PPT + bcol * NN + ki * 32 + g4 * 8);
        z = __builtin_amdgcn_mfma_f32_16x16x32_bf16(afr[ki], bf, z, 0, 0, 0);
      }
#pragma unroll
      for (int r = 0; r < 4; ++r) {
        const __bf16 vb = (__bf16)z[r];
        Zl[g4 * 4 + r][w * 64 + nt * 16 + r15] = __builtin_bit_cast(unsigned short, vb);
      }
    }
    __syncthreads();

    // --- Y phase: Y = Z @ g^T over k=d' (4-wave k-split), then (x)M reduce
    f32x4 acc = {0.f, 0.f, 0.f, 0.f};
#pragma unroll
    for (int k2 = 0; k2 < 2; ++k2) {
      const int kb = w * 64 + k2 * 32 + g4 * 8;
      const bf16x8 af = *(const bf16x8*)(&Zl[r15][kb]);
      const bf16x8 bf = load_bf8_f32(gb + (n0 + r15) * ND + kb);  // B[k][col]=g[col][k]
      acc = __builtin_amdgcn_mfma_f32_16x16x32_bf16(af, bf, acc, 0, 0, 0);
    }
    red[w][lane] = acc;
    __syncthreads();
    if (w == 0) {
      const f32x4 t = (red[0][lane] + red[1][lane]) + (red[2][lane] + red[3][lane]);
      float s = 0.0f;
#pragma unroll
      for (int r = 0; r < 4; ++r)
        s += t[r] * M[(m0 + g4 * 4 + r) * NN + (n0 + r15)];
      s = wave_reduce(s);
      if (lane == 0) pm[bid] = s;
    }
  } else {
    const int b = bid - 1024;
    p1s[tid] = p1[tid];
    __syncthreads();
    const float4 pv = *(const float4*)(&p1s[lane * 4]);
    float accs = 0.0f;
    for (int rr = 0; rr < 64; ++rr) {
      const int row = w * 64 + rr;
      const float4 gv = *(const float4*)(g + ((size_t)((b << 8) + row)) * ND + lane * 4);
      float s = gv.x * pv.x + gv.y * pv.y + gv.z * pv.z + gv.w * pv.w;
      s = wave_reduce(s);
      if (lane == 0) accs += M[row * (NN + 1)] * s;   // M diag weight
    }
    if (lane == 0) sp[w] = accs;
    __syncthreads();
    if (tid == 0) ps[b] = sp[0] + sp[1] + sp[2] + sp[3];
  }
}

// K3: single-block final combine.
// L = B*ns*lnK + (bt/K)*sum(ps) + (bt^2/(2K))*sum(pm);  out = (-L/(bt*ns) - 2*g2)/(B*N)
__global__ __launch_bounds__(256) void final_kernel(
    const float* __restrict__ pm, const float* __restrict__ ps,
    const float* __restrict__ pg2, const float* __restrict__ beta,
    const int ns, float* __restrict__ out) {
  __shared__ float sa[4], sb[4], sc[4];
  float sm2 = 0.f, sm1 = 0.f, sg = 0.f;
  for (int i = threadIdx.x; i < 1024; i += 256) sm2 += pm[i];
  if (threadIdx.x < 4) sm1 = ps[threadIdx.x];
  if (threadIdx.x < 32) sg = pg2[threadIdx.x];
  sm2 = wave_reduce(sm2);
  sm1 = wave_reduce(sm1);
  sg = wave_reduce(sg);
  const int lane = threadIdx.x & 63;
  const int w = threadIdx.x >> 6;
  if (lane == 0) { sa[w] = sm2; sb[w] = sm1; sc[w] = sg; }
  __syncthreads();
  if (threadIdx.x == 0) {
    const float m2t = sa[0] + sa[1] + sa[2] + sa[3];
    const float m1t = sb[0] + sb[1] + sb[2] + sb[3];
    const float g2t = sc[0] + sc[1] + sc[2] + sc[3];
    const float bt = beta[0];
    const float L = (float)NB * (float)ns * LN_NK
                  + (bt / (float)NK) * m1t
                  + (bt * bt * 0.5f / (float)NK) * m2t;
    const float ep = -L / (bt * (float)ns);
    out[0] = (ep - 2.0f * g2t) / (float)(NB * NN);
  }
}

extern "C" void kernel_launch(void* const* d_in, const int* in_sizes, int n_in,
                              void* d_out, int out_size, void* d_ws, size_t ws_size,
                              hipStream_t stream) {
  const float* g = (const float*)d_in[0];
  const float* patterns = (const float*)d_in[1];
  const float* beta = (const float*)d_in[2];
  const int* edges = (const int*)d_in[3];
  const int* triangles = (const int*)d_in[4];
  const int m_edge = in_sizes[3] / 2;   // 16320
  const int m_tri = in_sizes[4] / 3;    // 16320
  const int ns = m_edge + m_tri;

  // ws: PPT 128KB @0 | M 256KB @256KB | p1 @768KB | pm[1024] | ps[4] | pg2[32]
  ushort* PPT = (ushort*)d_ws;
  float* M = (float*)((char*)d_ws + (256u << 10));
  float* p1 = (float*)((char*)d_ws + (768u << 10));
  float* pm = p1 + 256;
  float* ps = pm + 1024;
  float* pg2 = ps + 4;
  float* out = (float*)d_out;

  hipLaunchKernelGGL(k1_kernel, dim3(K1_BLOCKS), dim3(256), 0, stream,
                     patterns, g, edges, m_edge, triangles, m_tri, PPT, M, p1, pg2);
  hipLaunchKernelGGL(k2_kernel, dim3(K2_BLOCKS), dim3(256), 0, stream,
                     g, PPT, M, p1, pm, ps);
  hipLaunchKernelGGL(final_kernel, dim3(1), dim3(256), 0, stream,
                     pm, ps, pg2, beta, ns, out);
}

// Round 17
// 59.486 us; speedup vs baseline: 1.5241x; 1.5241x over previous
//
#include <hip/hip_runtime.h>
#include <hip/hip_bf16.h>

#define NB 4
#define NN 256
#define ND 256
#define NK 1024
#define LN_NK 6.9314718055994531f   // ln(1024)

#define K1_BLOCKS 228   // 64 PPT | 64 M-rows | 64 gT | 4 p1 | 32 g2
#define K2_BLOCKS 260   // 256 Z.V tiles | 4 m1

typedef __bf16 bf16x8 __attribute__((ext_vector_type(8)));
typedef float f32x4 __attribute__((ext_vector_type(4)));
typedef unsigned short ushort8 __attribute__((ext_vector_type(8)));

__device__ __forceinline__ float wave_reduce(float s) {
#pragma unroll
  for (int m = 32; m >= 1; m >>= 1) s += __shfl_xor(s, m, 64);
  return s;
}

__device__ __forceinline__ bf16x8 load_bf8_f32(const float* p) {
  const float4 a0 = *(const float4*)p;
  const float4 a1 = *(const float4*)(p + 4);
  bf16x8 r;
  r[0] = (__bf16)a0.x; r[1] = (__bf16)a0.y; r[2] = (__bf16)a0.z; r[3] = (__bf16)a0.w;
  r[4] = (__bf16)a1.x; r[5] = (__bf16)a1.y; r[6] = (__bf16)a1.z; r[7] = (__bf16)a1.w;
  return r;
}

// K1: 0..63   PPT = P @ P^T (bf16; R11/R16-verified body)
//     64..127 M rows (4/block), own-row build with 8-deep batched loads
//     128..191 gT build: gT[b][d'][v] = bf16(g[b][v][d']), 64x64 LDS-transpose tiles
//     192..195 p1[d] = sum_k P[d,k]   (R16-verified)
//     196..227 g2 partials            (R16-verified)
__global__ __launch_bounds__(256) void k1_kernel(
    const float* __restrict__ P, const float* __restrict__ A,
    const int* __restrict__ edges, const int m_edge,
    const int* __restrict__ tris, const int m_tri,
    ushort* __restrict__ PPT, float* __restrict__ M, ushort* __restrict__ GT,
    float* __restrict__ p1, float* __restrict__ pg2) {
  __shared__ float Mloc[4][256];
  __shared__ ushort Tl[64][72];     // 144B row stride: 16B-aligned, pad vs conflicts
  __shared__ float sp[4];
  const int tid = threadIdx.x;
  const int lane = tid & 63;
  const int w = tid >> 6;
  const int bid = blockIdx.x;

  if (bid < 64) {
    // ---- PPT ----
    const int m0 = (bid >> 2) * 16;
    const int n0 = (bid & 3) * 64 + w * 16;
    const int r15 = lane & 15;
    const int g4 = lane >> 4;
    f32x4 acc = {0.f, 0.f, 0.f, 0.f};
#pragma unroll
    for (int kk = 0; kk < NK; kk += 32) {
      const int kb = kk + g4 * 8;   // same (group,elem)->k map for A and B => layout-safe
      const bf16x8 af = load_bf8_f32(P + (m0 + r15) * NK + kb);
      const bf16x8 bf = load_bf8_f32(P + (n0 + r15) * NK + kb);
      acc = __builtin_amdgcn_mfma_f32_16x16x32_bf16(af, bf, acc, 0, 0, 0);
    }
#pragma unroll
    for (int r = 0; r < 4; ++r) {
      const int orow = m0 + g4 * 4 + r;   // verified C/D map
      const __bf16 vb = (__bf16)acc[r];
      PPT[orow * NN + (n0 + r15)] = __builtin_bit_cast(unsigned short, vb);
    }
  } else if (bid < 128) {
    // ---- M rows [r0, r0+4): batched scan (8 loads in flight -> pipelined) ----
    const int r0 = (bid - 64) * 4;
    for (int c = tid; c < 1024; c += 256) ((float*)Mloc)[c] = 0.0f;
    __syncthreads();
    for (int base = 0; base < 16384; base += 2048) {
      int2 eb[8];
#pragma unroll
      for (int q = 0; q < 8; ++q) {
        const int idx = base + q * 256 + tid;
        if (idx < m_edge) eb[q] = ((const int2*)edges)[idx];
        else { eb[q].x = -100000; eb[q].y = -100000; }
      }
#pragma unroll
      for (int q = 0; q < 8; ++q) {
        const int u = eb[q].x, v = eb[q].y;
        const unsigned du = (unsigned)(u - r0), dv = (unsigned)(v - r0);
        if (du < 4u) { atomicAdd(&Mloc[du][u], 1.f); atomicAdd(&Mloc[du][v], 1.f); }
        if (dv < 4u) { atomicAdd(&Mloc[dv][v], 1.f); atomicAdd(&Mloc[dv][u], 1.f); }
      }
    }
    for (int base = 0; base < 16384; base += 2048) {
      int tb[8][3];
#pragma unroll
      for (int q = 0; q < 8; ++q) {
        const int idx = base + q * 256 + tid;
        if (idx < m_tri) {
          tb[q][0] = tris[3 * idx]; tb[q][1] = tris[3 * idx + 1]; tb[q][2] = tris[3 * idx + 2];
        } else { tb[q][0] = -100000; tb[q][1] = -100000; tb[q][2] = -100000; }
      }
#pragma unroll
      for (int q = 0; q < 8; ++q) {
        const int u = tb[q][0], v = tb[q][1], x = tb[q][2];
        const unsigned du = (unsigned)(u - r0), dv = (unsigned)(v - r0),
                       dx = (unsigned)(x - r0);
        if (du < 4u) { atomicAdd(&Mloc[du][u], 1.f); atomicAdd(&Mloc[du][v], 1.f);
                       atomicAdd(&Mloc[du][x], 1.f); }
        if (dv < 4u) { atomicAdd(&Mloc[dv][v], 1.f); atomicAdd(&Mloc[dv][u], 1.f);
                       atomicAdd(&Mloc[dv][x], 1.f); }
        if (dx < 4u) { atomicAdd(&Mloc[dx][x], 1.f); atomicAdd(&Mloc[dx][u], 1.f);
                       atomicAdd(&Mloc[dx][v], 1.f); }
      }
    }
    __syncthreads();
#pragma unroll
    for (int r = 0; r < 4; ++r) M[(r0 + r) * NN + tid] = Mloc[r][tid];
  } else if (bid < 192) {
    // ---- gT: one 64x64 tile (b, v0t, d0), LDS transpose, bf16 out ----
    const int idx = bid - 128;
    const int b = idx >> 4;
    const int t = idx & 15;
    const int v0t = (t >> 2) * 64;
    const int d0 = (t & 3) * 64;
    const int r = tid >> 2, q = tid & 3;
    const float* src = A + ((size_t)((b << 8) + v0t + r)) * ND + d0 + q * 16;
#pragma unroll
    for (int f = 0; f < 4; ++f) {
      const float4 v4 = *(const float4*)(src + f * 4);
      const __bf16 b0 = (__bf16)v4.x, b1 = (__bf16)v4.y, b2 = (__bf16)v4.z, b3 = (__bf16)v4.w;
      Tl[q * 16 + f * 4 + 0][r] = __builtin_bit_cast(unsigned short, b0);
      Tl[q * 16 + f * 4 + 1][r] = __builtin_bit_cast(unsigned short, b1);
      Tl[q * 16 + f * 4 + 2][r] = __builtin_bit_cast(unsigned short, b2);
      Tl[q * 16 + f * 4 + 3][r] = __builtin_bit_cast(unsigned short, b3);
    }
    __syncthreads();
    ushort* dst = GT + ((size_t)b << 16) + (d0 + r) * NN + v0t + q * 16;
    *(ushort8*)dst = *(const ushort8*)(&Tl[r][q * 16]);
    *(ushort8*)(dst + 8) = *(const ushort8*)(&Tl[r][q * 16 + 8]);
  } else if (bid < 196) {
    // ---- p1 ----
    const int base = (bid - 192) * 64 + w * 16;
#pragma unroll
    for (int jr = 0; jr < 16; ++jr) {
      const int row = base + jr;
      const float* pr = P + row * NK + lane * 16;
      float s = 0.0f;
#pragma unroll
      for (int q = 0; q < 4; ++q) {
        const float4 v = *(const float4*)(pr + q * 4);
        s += v.x + v.y + v.z + v.w;
      }
      s = wave_reduce(s);
      if (lane == 0) p1[row] = s;
    }
  } else {
    // ---- g2 ----
    const int gi = bid - 196;
    float s = 0.0f;
    for (int i = gi * 256 + tid; i < 65536; i += 32 * 256) {
      const float4 v = ((const float4*)A)[i];
      s += v.x * v.x + v.y * v.y + v.z * v.z + v.w * v.w;
    }
    s = wave_reduce(s);
    if (lane == 0) sp[w] = s;
    __syncthreads();
    if (tid == 0) pg2[gi] = sp[0] + sp[1] + sp[2] + sp[3];
  }
}

// K2: 0..255  per block: batch b, v-strip [v0,v0+16), d'-quarter [n0,n0+64);
//   wave w owns d'-tile col0 = n0+w*16. Computes Z-tile = rowdot(g_v, PPT_d')
//   and V-tile = rowdot(M_v, gT_d') with IDENTICAL A/B row maps -> element
//   (i,j) lands in the same (lane,reg) in both accs -> in-register Z.V reduce
//   is layout-immune. Block partial -> pm[bid].
//   256..259: m1 partials ps[b] = sum_v M[v][v]*(g_bv . p1)   (R16-verified body)
__global__ __launch_bounds__(256) void k2_kernel(
    const float* __restrict__ g, const ushort* __restrict__ PPT,
    const float* __restrict__ M, const ushort* __restrict__ GT,
    const float* __restrict__ p1, float* __restrict__ pm, float* __restrict__ ps) {
  __shared__ float sp[4];
  __shared__ float p1s[256];
  const int tid = threadIdx.x;
  const int lane = tid & 63;
  const int w = tid >> 6;
  const int bid = blockIdx.x;

  if (bid < 256) {
    const int b = bid >> 6;
    const int rem = bid & 63;
    const int v0 = (rem >> 2) * 16;
    const int col0 = (rem & 3) * 64 + w * 16;
    const int r15 = lane & 15;
    const int g4 = lane >> 4;

    bf16x8 gA[8], MA[8];
#pragma unroll
    for (int ki = 0; ki < 8; ++ki) {
      const int kb = ki * 32 + g4 * 8;
      gA[ki] = load_bf8_f32(g + ((size_t)((b << 8) + v0 + r15)) * ND + kb);
      MA[ki] = load_bf8_f32(M + (v0 + r15) * NN + kb);
    }
    f32x4 aZ = {0.f, 0.f, 0.f, 0.f};
    f32x4 aV = {0.f, 0.f, 0.f, 0.f};
#pragma unroll
    for (int ki = 0; ki < 8; ++ki) {
      const int kb = ki * 32 + g4 * 8;
      const bf16x8 bz = *(const bf16x8*)(PPT + (col0 + r15) * NN + kb);
      aZ = __builtin_amdgcn_mfma_f32_16x16x32_bf16(gA[ki], bz, aZ, 0, 0, 0);
      const bf16x8 bv = *(const bf16x8*)(GT + ((size_t)b << 16) + (col0 + r15) * NN + kb);
      aV = __builtin_amdgcn_mfma_f32_16x16x32_bf16(MA[ki], bv, aV, 0, 0, 0);
    }
    float s = aZ[0] * aV[0] + aZ[1] * aV[1] + aZ[2] * aV[2] + aZ[3] * aV[3];
    s = wave_reduce(s);
    if (lane == 0) sp[w] = s;
    __syncthreads();
    if (tid == 0) pm[bid] = sp[0] + sp[1] + sp[2] + sp[3];
  } else {
    const int b = bid - 256;
    p1s[tid] = p1[tid];
    __syncthreads();
    const float4 pv = *(const float4*)(&p1s[lane * 4]);
    float accs = 0.0f;
    for (int rr = 0; rr < 64; ++rr) {
      const int row = w * 64 + rr;
      const float4 gv = *(const float4*)(g + ((size_t)((b << 8) + row)) * ND + lane * 4);
      float s = gv.x * pv.x + gv.y * pv.y + gv.z * pv.z + gv.w * pv.w;
      s = wave_reduce(s);
      if (lane == 0) accs += M[row * (NN + 1)] * s;
    }
    if (lane == 0) sp[w] = accs;
    __syncthreads();
    if (tid == 0) ps[b] = sp[0] + sp[1] + sp[2] + sp[3];
  }
}

// K3: final combine (R16-verified formula)
__global__ __launch_bounds__(256) void final_kernel(
    const float* __restrict__ pm, const float* __restrict__ ps,
    const float* __restrict__ pg2, const float* __restrict__ beta,
    const int ns, float* __restrict__ out) {
  __shared__ float sa[4], sb[4], sc[4];
  float sm2 = 0.f, sm1 = 0.f, sg = 0.f;
  if (threadIdx.x < 256) sm2 = pm[threadIdx.x];
  if (threadIdx.x < 4) sm1 = ps[threadIdx.x];
  if (threadIdx.x < 32) sg = pg2[threadIdx.x];
  sm2 = wave_reduce(sm2);
  sm1 = wave_reduce(sm1);
  sg = wave_reduce(sg);
  const int lane = threadIdx.x & 63;
  const int w = threadIdx.x >> 6;
  if (lane == 0) { sa[w] = sm2; sb[w] = sm1; sc[w] = sg; }
  __syncthreads();
  if (threadIdx.x == 0) {
    const float m2t = sa[0] + sa[1] + sa[2] + sa[3];
    const float m1t = sb[0] + sb[1] + sb[2] + sb[3];
    const float g2t = sc[0] + sc[1] + sc[2] + sc[3];
    const float bt = beta[0];
    const float L = (float)NB * (float)ns * LN_NK
                  + (bt / (float)NK) * m1t
                  + (bt * bt * 0.5f / (float)NK) * m2t;
    const float ep = -L / (bt * (float)ns);
    out[0] = (ep - 2.0f * g2t) / (float)(NB * NN);
  }
}

extern "C" void kernel_launch(void* const* d_in, const int* in_sizes, int n_in,
                              void* d_out, int out_size, void* d_ws, size_t ws_size,
                              hipStream_t stream) {
  const float* g = (const float*)d_in[0];
  const float* patterns = (const float*)d_in[1];
  const float* beta = (const float*)d_in[2];
  const int* edges = (const int*)d_in[3];
  const int* triangles = (const int*)d_in[4];
  const int m_edge = in_sizes[3] / 2;   // 16320
  const int m_tri = in_sizes[4] / 3;    // 16320
  const int ns = m_edge + m_tri;

  // ws: PPT 128K @0 | M f32 256K @128K | GT bf16 512K @384K | p1/pm/ps/pg2 @896K
  ushort* PPT = (ushort*)d_ws;
  float* M = (float*)((char*)d_ws + (128u << 10));
  ushort* GT = (ushort*)((char*)d_ws + (384u << 10));
  float* p1 = (float*)((char*)d_ws + (896u << 10));
  float* pm = p1 + 256;
  float* ps = pm + 256;
  float* pg2 = ps + 4;
  float* out = (float*)d_out;

  hipLaunchKernelGGL(k1_kernel, dim3(K1_BLOCKS), dim3(256), 0, stream,
                     patterns, g, edges, m_edge, triangles, m_tri,
                     PPT, M, GT, p1, pg2);
  hipLaunchKernelGGL(k2_kernel, dim3(K2_BLOCKS), dim3(256), 0, stream,
                     g, PPT, M, GT, p1, pm, ps);
  hipLaunchKernelGGL(final_kernel, dim3(1), dim3(256), 0, stream,
                     pm, ps, pg2, beta, ns, out);
}

// Round 18
// 57.872 us; speedup vs baseline: 1.5666x; 1.0279x over previous
//
#include <hip/hip_runtime.h>
#include <hip/hip_bf16.h>

#define NB 4
#define NN 256
#define ND 256
#define NK 1024
#define LN_NK 6.9314718055994531f   // ln(1024)

#define K1_BLOCKS 228   // 64 PPT | 64 M-rows | 64 gT | 4 p1 | 32 g2
#define K2_BLOCKS 260   // 256 Z.V tiles | 4 m1

typedef __bf16 bf16x8 __attribute__((ext_vector_type(8)));
typedef float f32x4 __attribute__((ext_vector_type(4)));
typedef unsigned short ushort8 __attribute__((ext_vector_type(8)));

__device__ __forceinline__ float wave_reduce(float s) {
#pragma unroll
  for (int m = 32; m >= 1; m >>= 1) s += __shfl_xor(s, m, 64);
  return s;
}

__device__ __forceinline__ bf16x8 load_bf8_f32(const float* p) {
  const float4 a0 = *(const float4*)p;
  const float4 a1 = *(const float4*)(p + 4);
  bf16x8 r;
  r[0] = (__bf16)a0.x; r[1] = (__bf16)a0.y; r[2] = (__bf16)a0.z; r[3] = (__bf16)a0.w;
  r[4] = (__bf16)a1.x; r[5] = (__bf16)a1.y; r[6] = (__bf16)a1.z; r[7] = (__bf16)a1.w;
  return r;
}

// K1: identical to R17 (absent from top-5 -> fast enough).
//     0..63   PPT = P @ P^T (bf16; R11/R16-verified body)
//     64..127 M rows (4/block), own-row build, 8-deep batched loads
//     128..191 gT build: gT[b][d'][v] = bf16(g[b][v][d'])
//     192..195 p1 | 196..227 g2
__global__ __launch_bounds__(256) void k1_kernel(
    const float* __restrict__ P, const float* __restrict__ A,
    const int* __restrict__ edges, const int m_edge,
    const int* __restrict__ tris, const int m_tri,
    ushort* __restrict__ PPT, float* __restrict__ M, ushort* __restrict__ GT,
    float* __restrict__ p1, float* __restrict__ pg2) {
  __shared__ float Mloc[4][256];
  __shared__ ushort Tl[64][72];
  __shared__ float sp[4];
  const int tid = threadIdx.x;
  const int lane = tid & 63;
  const int w = tid >> 6;
  const int bid = blockIdx.x;

  if (bid < 64) {
    const int m0 = (bid >> 2) * 16;
    const int n0 = (bid & 3) * 64 + w * 16;
    const int r15 = lane & 15;
    const int g4 = lane >> 4;
    f32x4 acc = {0.f, 0.f, 0.f, 0.f};
#pragma unroll
    for (int kk = 0; kk < NK; kk += 32) {
      const int kb = kk + g4 * 8;   // same (group,elem)->k map for A and B => layout-safe
      const bf16x8 af = load_bf8_f32(P + (m0 + r15) * NK + kb);
      const bf16x8 bf = load_bf8_f32(P + (n0 + r15) * NK + kb);
      acc = __builtin_amdgcn_mfma_f32_16x16x32_bf16(af, bf, acc, 0, 0, 0);
    }
#pragma unroll
    for (int r = 0; r < 4; ++r) {
      const int orow = m0 + g4 * 4 + r;   // verified C/D map
      const __bf16 vb = (__bf16)acc[r];
      PPT[orow * NN + (n0 + r15)] = __builtin_bit_cast(unsigned short, vb);
    }
  } else if (bid < 128) {
    const int r0 = (bid - 64) * 4;
    for (int c = tid; c < 1024; c += 256) ((float*)Mloc)[c] = 0.0f;
    __syncthreads();
    for (int base = 0; base < 16384; base += 2048) {
      int2 eb[8];
#pragma unroll
      for (int q = 0; q < 8; ++q) {
        const int idx = base + q * 256 + tid;
        if (idx < m_edge) eb[q] = ((const int2*)edges)[idx];
        else { eb[q].x = -100000; eb[q].y = -100000; }
      }
#pragma unroll
      for (int q = 0; q < 8; ++q) {
        const int u = eb[q].x, v = eb[q].y;
        const unsigned du = (unsigned)(u - r0), dv = (unsigned)(v - r0);
        if (du < 4u) { atomicAdd(&Mloc[du][u], 1.f); atomicAdd(&Mloc[du][v], 1.f); }
        if (dv < 4u) { atomicAdd(&Mloc[dv][v], 1.f); atomicAdd(&Mloc[dv][u], 1.f); }
      }
    }
    for (int base = 0; base < 16384; base += 2048) {
      int tb[8][3];
#pragma unroll
      for (int q = 0; q < 8; ++q) {
        const int idx = base + q * 256 + tid;
        if (idx < m_tri) {
          tb[q][0] = tris[3 * idx]; tb[q][1] = tris[3 * idx + 1]; tb[q][2] = tris[3 * idx + 2];
        } else { tb[q][0] = -100000; tb[q][1] = -100000; tb[q][2] = -100000; }
      }
#pragma unroll
      for (int q = 0; q < 8; ++q) {
        const int u = tb[q][0], v = tb[q][1], x = tb[q][2];
        const unsigned du = (unsigned)(u - r0), dv = (unsigned)(v - r0),
                       dx = (unsigned)(x - r0);
        if (du < 4u) { atomicAdd(&Mloc[du][u], 1.f); atomicAdd(&Mloc[du][v], 1.f);
                       atomicAdd(&Mloc[du][x], 1.f); }
        if (dv < 4u) { atomicAdd(&Mloc[dv][v], 1.f); atomicAdd(&Mloc[dv][u], 1.f);
                       atomicAdd(&Mloc[dv][x], 1.f); }
        if (dx < 4u) { atomicAdd(&Mloc[dx][x], 1.f); atomicAdd(&Mloc[dx][u], 1.f);
                       atomicAdd(&Mloc[dx][v], 1.f); }
      }
    }
    __syncthreads();
#pragma unroll
    for (int r = 0; r < 4; ++r) M[(r0 + r) * NN + tid] = Mloc[r][tid];
  } else if (bid < 192) {
    const int idx = bid - 128;
    const int b = idx >> 4;
    const int t = idx & 15;
    const int v0t = (t >> 2) * 64;
    const int d0 = (t & 3) * 64;
    const int r = tid >> 2, q = tid & 3;
    const float* src = A + ((size_t)((b << 8) + v0t + r)) * ND + d0 + q * 16;
#pragma unroll
    for (int f = 0; f < 4; ++f) {
      const float4 v4 = *(const float4*)(src + f * 4);
      const __bf16 b0 = (__bf16)v4.x, b1 = (__bf16)v4.y, b2 = (__bf16)v4.z, b3 = (__bf16)v4.w;
      Tl[q * 16 + f * 4 + 0][r] = __builtin_bit_cast(unsigned short, b0);
      Tl[q * 16 + f * 4 + 1][r] = __builtin_bit_cast(unsigned short, b1);
      Tl[q * 16 + f * 4 + 2][r] = __builtin_bit_cast(unsigned short, b2);
      Tl[q * 16 + f * 4 + 3][r] = __builtin_bit_cast(unsigned short, b3);
    }
    __syncthreads();
    ushort* dst = GT + ((size_t)b << 16) + (d0 + r) * NN + v0t + q * 16;
    *(ushort8*)dst = *(const ushort8*)(&Tl[r][q * 16]);
    *(ushort8*)(dst + 8) = *(const ushort8*)(&Tl[r][q * 16 + 8]);
  } else if (bid < 196) {
    const int base = (bid - 192) * 64 + w * 16;
#pragma unroll
    for (int jr = 0; jr < 16; ++jr) {
      const int row = base + jr;
      const float* pr = P + row * NK + lane * 16;
      float s = 0.0f;
#pragma unroll
      for (int q = 0; q < 4; ++q) {
        const float4 v = *(const float4*)(pr + q * 4);
        s += v.x + v.y + v.z + v.w;
      }
      s = wave_reduce(s);
      if (lane == 0) p1[row] = s;
    }
  } else {
    const int gi = bid - 196;
    float s = 0.0f;
    for (int i = gi * 256 + tid; i < 65536; i += 32 * 256) {
      const float4 v = ((const float4*)A)[i];
      s += v.x * v.x + v.y * v.y + v.z * v.z + v.w * v.w;
    }
    s = wave_reduce(s);
    if (lane == 0) sp[w] = s;
    __syncthreads();
    if (tid == 0) pg2[gi] = sp[0] + sp[1] + sp[2] + sp[3];
  }
}

// K2: same math/geometry as R17, but STREAMING fragments (no prefetch arrays ->
// no scratch spill; R17's VGPR=36 + 16 fragment arrays = spilled, 39us).
// Per ki: load {g,PPT} -> MFMA-Z, load {M,GT} -> MFMA-V; nothing live across iters.
//   0..255: batch b, v-strip [v0,v0+16), wave-owned d'-tile col0. Z=rowdot(g,PPT),
//   V=rowdot(M,gT); identical A/B row maps -> in-register Z.V reduce layout-immune.
//   256..259: m1 partials ps[b] (exact f32, R16-verified body).
__global__ __launch_bounds__(256) void k2_kernel(
    const float* __restrict__ g, const ushort* __restrict__ PPT,
    const float* __restrict__ M, const ushort* __restrict__ GT,
    const float* __restrict__ p1, float* __restrict__ pm, float* __restrict__ ps) {
  __shared__ float sp[4];
  __shared__ float p1s[256];
  const int tid = threadIdx.x;
  const int lane = tid & 63;
  const int w = tid >> 6;
  const int bid = blockIdx.x;

  if (bid < 256) {
    const int b = bid >> 6;
    const int rem = bid & 63;
    const int v0 = (rem >> 2) * 16;
    const int col0 = (rem & 3) * 64 + w * 16;
    const int r15 = lane & 15;
    const int g4 = lane >> 4;
    const float* grow = g + ((size_t)((b << 8) + v0 + r15)) * ND;
    const float* mrow = M + (v0 + r15) * NN;
    const ushort* zrow = PPT + (col0 + r15) * NN;
    const ushort* vrow = GT + ((size_t)b << 16) + (col0 + r15) * NN;

    f32x4 aZ = {0.f, 0.f, 0.f, 0.f};
    f32x4 aV = {0.f, 0.f, 0.f, 0.f};
#pragma unroll
    for (int ki = 0; ki < 8; ++ki) {
      const int kb = ki * 32 + g4 * 8;   // same k-map for A and B => layout-safe
      const bf16x8 ga = load_bf8_f32(grow + kb);
      const bf16x8 bz = *(const bf16x8*)(zrow + kb);
      aZ = __builtin_amdgcn_mfma_f32_16x16x32_bf16(ga, bz, aZ, 0, 0, 0);
      const bf16x8 ma = load_bf8_f32(mrow + kb);
      const bf16x8 bv = *(const bf16x8*)(vrow + kb);
      aV = __builtin_amdgcn_mfma_f32_16x16x32_bf16(ma, bv, aV, 0, 0, 0);
    }
    float s = aZ[0] * aV[0] + aZ[1] * aV[1] + aZ[2] * aV[2] + aZ[3] * aV[3];
    s = wave_reduce(s);
    if (lane == 0) sp[w] = s;
    __syncthreads();
    if (tid == 0) pm[bid] = sp[0] + sp[1] + sp[2] + sp[3];
  } else {
    const int b = bid - 256;
    p1s[tid] = p1[tid];
    __syncthreads();
    const float4 pv = *(const float4*)(&p1s[lane * 4]);
    float accs = 0.0f;
    for (int rr = 0; rr < 64; ++rr) {
      const int row = w * 64 + rr;
      const float4 gv = *(const float4*)(g + ((size_t)((b << 8) + row)) * ND + lane * 4);
      float s = gv.x * pv.x + gv.y * pv.y + gv.z * pv.z + gv.w * pv.w;
      s = wave_reduce(s);
      if (lane == 0) accs += M[row * (NN + 1)] * s;
    }
    if (lane == 0) sp[w] = accs;
    __syncthreads();
    if (tid == 0) ps[b] = sp[0] + sp[1] + sp[2] + sp[3];
  }
}

// K3: final combine (R16-verified formula)
__global__ __launch_bounds__(256) void final_kernel(
    const float* __restrict__ pm, const float* __restrict__ ps,
    const float* __restrict__ pg2, const float* __restrict__ beta,
    const int ns, float* __restrict__ out) {
  __shared__ float sa[4], sb[4], sc[4];
  float sm2 = 0.f, sm1 = 0.f, sg = 0.f;
  if (threadIdx.x < 256) sm2 = pm[threadIdx.x];
  if (threadIdx.x < 4) sm1 = ps[threadIdx.x];
  if (threadIdx.x < 32) sg = pg2[threadIdx.x];
  sm2 = wave_reduce(sm2);
  sm1 = wave_reduce(sm1);
  sg = wave_reduce(sg);
  const int lane = threadIdx.x & 63;
  const int w = threadIdx.x >> 6;
  if (lane == 0) { sa[w] = sm2; sb[w] = sm1; sc[w] = sg; }
  __syncthreads();
  if (threadIdx.x == 0) {
    const float m2t = sa[0] + sa[1] + sa[2] + sa[3];
    const float m1t = sb[0] + sb[1] + sb[2] + sb[3];
    const float g2t = sc[0] + sc[1] + sc[2] + sc[3];
    const float bt = beta[0];
    const float L = (float)NB * (float)ns * LN_NK
                  + (bt / (float)NK) * m1t
                  + (bt * bt * 0.5f / (float)NK) * m2t;
    const float ep = -L / (bt * (float)ns);
    out[0] = (ep - 2.0f * g2t) / (float)(NB * NN);
  }
}

extern "C" void kernel_launch(void* const* d_in, const int* in_sizes, int n_in,
                              void* d_out, int out_size, void* d_ws, size_t ws_size,
                              hipStream_t stream) {
  const float* g = (const float*)d_in[0];
  const float* patterns = (const float*)d_in[1];
  const float* beta = (const float*)d_in[2];
  const int* edges = (const int*)d_in[3];
  const int* triangles = (const int*)d_in[4];
  const int m_edge = in_sizes[3] / 2;   // 16320
  const int m_tri = in_sizes[4] / 3;    // 16320
  const int ns = m_edge + m_tri;

  // ws: PPT 128K @0 | M f32 256K @128K | GT bf16 512K @384K | p1/pm/ps/pg2 @896K
  ushort* PPT = (ushort*)d_ws;
  float* M = (float*)((char*)d_ws + (128u << 10));
  ushort* GT = (ushort*)((char*)d_ws + (384u << 10));
  float* p1 = (float*)((char*)d_ws + (896u << 10));
  float* pm = p1 + 256;
  float* ps = pm + 256;
  float* pg2 = ps + 4;
  float* out = (float*)d_out;

  hipLaunchKernelGGL(k1_kernel, dim3(K1_BLOCKS), dim3(256), 0, stream,
                     patterns, g, edges, m_edge, triangles, m_tri,
                     PPT, M, GT, p1, pg2);
  hipLaunchKernelGGL(k2_kernel, dim3(K2_BLOCKS), dim3(256), 0, stream,
                     g, PPT, M, GT, p1, pm, ps);
  hipLaunchKernelGGL(final_kernel, dim3(1), dim3(256), 0, stream,
                     pm, ps, pg2, beta, ns, out);
}

// Round 19
// 40.331 us; speedup vs baseline: 2.2480x; 1.4349x over previous
//
#include <hip/hip_runtime.h>
#include <hip/hip_bf16.h>

#define NB 4
#define NN 256
#define ND 256
#define NK 1024
#define LN_NK 6.9314718055994531f   // ln(1024)

#define K1_BLOCKS 228   // 64 PPT | 64 M-rows | 64 gT | 4 p1 | 32 g2
#define K2_BLOCKS 260   // 256 Z.V tiles | 4 m1

typedef __bf16 bf16x8 __attribute__((ext_vector_type(8)));
typedef float f32x4 __attribute__((ext_vector_type(4)));
typedef unsigned short ushort8 __attribute__((ext_vector_type(8)));

__device__ __forceinline__ float wave_reduce(float s) {
#pragma unroll
  for (int m = 32; m >= 1; m >>= 1) s += __shfl_xor(s, m, 64);
  return s;
}

__device__ __forceinline__ bf16x8 load_bf8_f32(const float* p) {
  const float4 a0 = *(const float4*)p;
  const float4 a1 = *(const float4*)(p + 4);
  bf16x8 r;
  r[0] = (__bf16)a0.x; r[1] = (__bf16)a0.y; r[2] = (__bf16)a0.z; r[3] = (__bf16)a0.w;
  r[4] = (__bf16)a1.x; r[5] = (__bf16)a1.y; r[6] = (__bf16)a1.z; r[7] = (__bf16)a1.w;
  return r;
}

// K1: 0..63 PPT | 64..127 M-rows | 128..191 gT | 192..195 p1 (PARALLELIZED)
//     | 196..227 g2.  (R17/R18 bodies except p1: serial wave_reduce loop removed)
__global__ __launch_bounds__(256) void k1_kernel(
    const float* __restrict__ P, const float* __restrict__ A,
    const int* __restrict__ edges, const int m_edge,
    const int* __restrict__ tris, const int m_tri,
    ushort* __restrict__ PPT, float* __restrict__ M, ushort* __restrict__ GT,
    float* __restrict__ p1, float* __restrict__ pg2) {
  __shared__ float Mloc[4][256];
  __shared__ ushort Tl[64][72];
  __shared__ float sp[4];
  const int tid = threadIdx.x;
  const int lane = tid & 63;
  const int w = tid >> 6;
  const int bid = blockIdx.x;

  if (bid < 64) {
    const int m0 = (bid >> 2) * 16;
    const int n0 = (bid & 3) * 64 + w * 16;
    const int r15 = lane & 15;
    const int g4 = lane >> 4;
    f32x4 acc = {0.f, 0.f, 0.f, 0.f};
#pragma unroll
    for (int kk = 0; kk < NK; kk += 32) {
      const int kb = kk + g4 * 8;   // same (group,elem)->k map for A and B => layout-safe
      const bf16x8 af = load_bf8_f32(P + (m0 + r15) * NK + kb);
      const bf16x8 bf = load_bf8_f32(P + (n0 + r15) * NK + kb);
      acc = __builtin_amdgcn_mfma_f32_16x16x32_bf16(af, bf, acc, 0, 0, 0);
    }
#pragma unroll
    for (int r = 0; r < 4; ++r) {
      const int orow = m0 + g4 * 4 + r;   // verified C/D map
      const __bf16 vb = (__bf16)acc[r];
      PPT[orow * NN + (n0 + r15)] = __builtin_bit_cast(unsigned short, vb);
    }
  } else if (bid < 128) {
    const int r0 = (bid - 64) * 4;
    for (int c = tid; c < 1024; c += 256) ((float*)Mloc)[c] = 0.0f;
    __syncthreads();
    for (int base = 0; base < 16384; base += 2048) {
      int2 eb[8];
#pragma unroll
      for (int q = 0; q < 8; ++q) {
        const int idx = base + q * 256 + tid;
        if (idx < m_edge) eb[q] = ((const int2*)edges)[idx];
        else { eb[q].x = -100000; eb[q].y = -100000; }
      }
#pragma unroll
      for (int q = 0; q < 8; ++q) {
        const int u = eb[q].x, v = eb[q].y;
        const unsigned du = (unsigned)(u - r0), dv = (unsigned)(v - r0);
        if (du < 4u) { atomicAdd(&Mloc[du][u], 1.f); atomicAdd(&Mloc[du][v], 1.f); }
        if (dv < 4u) { atomicAdd(&Mloc[dv][v], 1.f); atomicAdd(&Mloc[dv][u], 1.f); }
      }
    }
    for (int base = 0; base < 16384; base += 2048) {
      int tb[8][3];
#pragma unroll
      for (int q = 0; q < 8; ++q) {
        const int idx = base + q * 256 + tid;
        if (idx < m_tri) {
          tb[q][0] = tris[3 * idx]; tb[q][1] = tris[3 * idx + 1]; tb[q][2] = tris[3 * idx + 2];
        } else { tb[q][0] = -100000; tb[q][1] = -100000; tb[q][2] = -100000; }
      }
#pragma unroll
      for (int q = 0; q < 8; ++q) {
        const int u = tb[q][0], v = tb[q][1], x = tb[q][2];
        const unsigned du = (unsigned)(u - r0), dv = (unsigned)(v - r0),
                       dx = (unsigned)(x - r0);
        if (du < 4u) { atomicAdd(&Mloc[du][u], 1.f); atomicAdd(&Mloc[du][v], 1.f);
                       atomicAdd(&Mloc[du][x], 1.f); }
        if (dv < 4u) { atomicAdd(&Mloc[dv][v], 1.f); atomicAdd(&Mloc[dv][u], 1.f);
                       atomicAdd(&Mloc[dv][x], 1.f); }
        if (dx < 4u) { atomicAdd(&Mloc[dx][x], 1.f); atomicAdd(&Mloc[dx][u], 1.f);
                       atomicAdd(&Mloc[dx][v], 1.f); }
      }
    }
    __syncthreads();
#pragma unroll
    for (int r = 0; r < 4; ++r) M[(r0 + r) * NN + tid] = Mloc[r][tid];
  } else if (bid < 192) {
    const int idx = bid - 128;
    const int b = idx >> 4;
    const int t = idx & 15;
    const int v0t = (t >> 2) * 64;
    const int d0 = (t & 3) * 64;
    const int r = tid >> 2, q = tid & 3;
    const float* src = A + ((size_t)((b << 8) + v0t + r)) * ND + d0 + q * 16;
#pragma unroll
    for (int f = 0; f < 4; ++f) {
      const float4 v4 = *(const float4*)(src + f * 4);
      const __bf16 b0 = (__bf16)v4.x, b1 = (__bf16)v4.y, b2 = (__bf16)v4.z, b3 = (__bf16)v4.w;
      Tl[q * 16 + f * 4 + 0][r] = __builtin_bit_cast(unsigned short, b0);
      Tl[q * 16 + f * 4 + 1][r] = __builtin_bit_cast(unsigned short, b1);
      Tl[q * 16 + f * 4 + 2][r] = __builtin_bit_cast(unsigned short, b2);
      Tl[q * 16 + f * 4 + 3][r] = __builtin_bit_cast(unsigned short, b3);
    }
    __syncthreads();
    ushort* dst = GT + ((size_t)b << 16) + (d0 + r) * NN + v0t + q * 16;
    *(ushort8*)dst = *(const ushort8*)(&Tl[r][q * 16]);
    *(ushort8*)(dst + 8) = *(const ushort8*)(&Tl[r][q * 16 + 8]);
  } else if (bid < 196) {
    // ---- p1 PARALLEL: 4 threads per row (quad shfl), no serial loop ----
    const int row = (bid - 192) * 64 + (tid >> 2);
    const int q = tid & 3;
    const float* pr = P + row * NK + q * 256;
    float s = 0.0f;
#pragma unroll 8
    for (int i = 0; i < 64; ++i) {
      const float4 v = *(const float4*)(pr + i * 4);
      s += (v.x + v.y) + (v.z + v.w);
    }
    s += __shfl_xor(s, 1, 64);   // quad-local: lanes 4r..4r+3
    s += __shfl_xor(s, 2, 64);
    if (q == 0) p1[row] = s;
  } else {
    const int gi = bid - 196;
    float s = 0.0f;
    for (int i = gi * 256 + tid; i < 65536; i += 32 * 256) {
      const float4 v = ((const float4*)A)[i];
      s += v.x * v.x + v.y * v.y + v.z * v.z + v.w * v.w;
    }
    s = wave_reduce(s);
    if (lane == 0) sp[w] = s;
    __syncthreads();
    if (tid == 0) pg2[gi] = sp[0] + sp[1] + sp[2] + sp[3];
  }
}

// K2: 0..255 Z.V tiles (R18 streaming body, verified) |
//     256..259 m1 PARALLELIZED: one THREAD per row (was: 64 serial wave_reduces
//     per wave = the 39.7us tail, R18 counters: occ 2.8%, VALU 0.9%, warm==cold).
__global__ __launch_bounds__(256) void k2_kernel(
    const float* __restrict__ g, const ushort* __restrict__ PPT,
    const float* __restrict__ M, const ushort* __restrict__ GT,
    const float* __restrict__ p1, float* __restrict__ pm, float* __restrict__ ps) {
  __shared__ float sp[4];
  __shared__ float p1s[256];
  const int tid = threadIdx.x;
  const int lane = tid & 63;
  const int w = tid >> 6;
  const int bid = blockIdx.x;

  if (bid < 256) {
    const int b = bid >> 6;
    const int rem = bid & 63;
    const int v0 = (rem >> 2) * 16;
    const int col0 = (rem & 3) * 64 + w * 16;
    const int r15 = lane & 15;
    const int g4 = lane >> 4;
    const float* grow = g + ((size_t)((b << 8) + v0 + r15)) * ND;
    const float* mrow = M + (v0 + r15) * NN;
    const ushort* zrow = PPT + (col0 + r15) * NN;
    const ushort* vrow = GT + ((size_t)b << 16) + (col0 + r15) * NN;

    f32x4 aZ = {0.f, 0.f, 0.f, 0.f};
    f32x4 aV = {0.f, 0.f, 0.f, 0.f};
#pragma unroll
    for (int ki = 0; ki < 8; ++ki) {
      const int kb = ki * 32 + g4 * 8;   // same k-map for A and B => layout-safe
      const bf16x8 ga = load_bf8_f32(grow + kb);
      const bf16x8 bz = *(const bf16x8*)(zrow + kb);
      aZ = __builtin_amdgcn_mfma_f32_16x16x32_bf16(ga, bz, aZ, 0, 0, 0);
      const bf16x8 ma = load_bf8_f32(mrow + kb);
      const bf16x8 bv = *(const bf16x8*)(vrow + kb);
      aV = __builtin_amdgcn_mfma_f32_16x16x32_bf16(ma, bv, aV, 0, 0, 0);
    }
    float s = aZ[0] * aV[0] + aZ[1] * aV[1] + aZ[2] * aV[2] + aZ[3] * aV[3];
    s = wave_reduce(s);
    if (lane == 0) sp[w] = s;
    __syncthreads();
    if (tid == 0) pm[bid] = sp[0] + sp[1] + sp[2] + sp[3];
  } else {
    // m1: thread tid owns row tid of batch b; 64 independent float4 loads;
    // weight by M-diag BEFORE the single tree reduce -> no serial chain.
    const int b = bid - 256;
    p1s[tid] = p1[tid];
    __syncthreads();
    const float* grow = g + ((size_t)((b << 8) + tid)) * ND;
    float s = 0.0f;
#pragma unroll 8
    for (int qq = 0; qq < 64; ++qq) {
      const float4 gv = *(const float4*)(grow + qq * 4);
      const float4 pv = *(const float4*)(&p1s[qq * 4]);   // LDS broadcast
      s = fmaf(gv.x, pv.x, s); s = fmaf(gv.y, pv.y, s);
      s = fmaf(gv.z, pv.z, s); s = fmaf(gv.w, pv.w, s);
    }
    s *= M[tid * (NN + 1)];        // diag weight, per-thread (parallel)
    s = wave_reduce(s);
    if (lane == 0) sp[w] = s;
    __syncthreads();
    if (tid == 0) ps[b] = sp[0] + sp[1] + sp[2] + sp[3];
  }
}

// K3: final combine (R16-verified formula)
__global__ __launch_bounds__(256) void final_kernel(
    const float* __restrict__ pm, const float* __restrict__ ps,
    const float* __restrict__ pg2, const float* __restrict__ beta,
    const int ns, float* __restrict__ out) {
  __shared__ float sa[4], sb[4], sc[4];
  float sm2 = 0.f, sm1 = 0.f, sg = 0.f;
  if (threadIdx.x < 256) sm2 = pm[threadIdx.x];
  if (threadIdx.x < 4) sm1 = ps[threadIdx.x];
  if (threadIdx.x < 32) sg = pg2[threadIdx.x];
  sm2 = wave_reduce(sm2);
  sm1 = wave_reduce(sm1);
  sg = wave_reduce(sg);
  const int lane = threadIdx.x & 63;
  const int w = threadIdx.x >> 6;
  if (lane == 0) { sa[w] = sm2; sb[w] = sm1; sc[w] = sg; }
  __syncthreads();
  if (threadIdx.x == 0) {
    const float m2t = sa[0] + sa[1] + sa[2] + sa[3];
    const float m1t = sb[0] + sb[1] + sb[2] + sb[3];
    const float g2t = sc[0] + sc[1] + sc[2] + sc[3];
    const float bt = beta[0];
    const float L = (float)NB * (float)ns * LN_NK
                  + (bt / (float)NK) * m1t
                  + (bt * bt * 0.5f / (float)NK) * m2t;
    const float ep = -L / (bt * (float)ns);
    out[0] = (ep - 2.0f * g2t) / (float)(NB * NN);
  }
}

extern "C" void kernel_launch(void* const* d_in, const int* in_sizes, int n_in,
                              void* d_out, int out_size, void* d_ws, size_t ws_size,
                              hipStream_t stream) {
  const float* g = (const float*)d_in[0];
  const float* patterns = (const float*)d_in[1];
  const float* beta = (const float*)d_in[2];
  const int* edges = (const int*)d_in[3];
  const int* triangles = (const int*)d_in[4];
  const int m_edge = in_sizes[3] / 2;   // 16320
  const int m_tri = in_sizes[4] / 3;    // 16320
  const int ns = m_edge + m_tri;

  // ws: PPT 128K @0 | M f32 256K @128K | GT bf16 512K @384K | p1/pm/ps/pg2 @896K
  ushort* PPT = (ushort*)d_ws;
  float* M = (float*)((char*)d_ws + (128u << 10));
  ushort* GT = (ushort*)((char*)d_ws + (384u << 10));
  float* p1 = (float*)((char*)d_ws + (896u << 10));
  float* pm = p1 + 256;
  float* ps = pm + 256;
  float* pg2 = ps + 4;
  float* out = (float*)d_out;

  hipLaunchKernelGGL(k1_kernel, dim3(K1_BLOCKS), dim3(256), 0, stream,
                     patterns, g, edges, m_edge, triangles, m_tri,
                     PPT, M, GT, p1, pg2);
  hipLaunchKernelGGL(k2_kernel, dim3(K2_BLOCKS), dim3(256), 0, stream,
                     g, PPT, M, GT, p1, pm, ps);
  hipLaunchKernelGGL(final_kernel, dim3(1), dim3(256), 0, stream,
                     pm, ps, pg2, beta, ns, out);
}

// Round 20
// 30.565 us; speedup vs baseline: 2.9663x; 1.3195x over previous
//
#include <hip/hip_runtime.h>
#include <hip/hip_bf16.h>

#define NB 4
#define NN 256
#define ND 256
#define NK 1024
#define LN_NK 6.9314718055994531f   // ln(1024)

#define K1_BLOCKS 1056              // 1024 gemm tiles + 32 g2
#define K2_BLOCKS 544               // gram upper-tri tiles: 4b x 136 (i<=j)
#define K3_BLOCKS 510               // 130560 simplex threads, 1 thread/task

typedef __bf16 bf16x8 __attribute__((ext_vector_type(8)));
typedef float f32x4 __attribute__((ext_vector_type(4)));
typedef float f32x2 __attribute__((ext_vector_type(2)));

__device__ __forceinline__ float wave_reduce(float s) {
#pragma unroll
  for (int m = 32; m >= 1; m >>= 1) s += __shfl_xor(s, m, 64);
  return s;
}

// sum of 8 fp8 (e4m3) bytes as floats
__device__ __forceinline__ float fp8x8_sum(long long v) {
  const unsigned lo = (unsigned)(v & 0xffffffffLL);
  const unsigned hi = (unsigned)((unsigned long long)v >> 32);
  const f32x2 a = __builtin_amdgcn_cvt_pk_f32_fp8(lo, false);
  const f32x2 b = __builtin_amdgcn_cvt_pk_f32_fp8(lo, true);
  const f32x2 c = __builtin_amdgcn_cvt_pk_f32_fp8(hi, false);
  const f32x2 d = __builtin_amdgcn_cvt_pk_f32_fp8(hi, true);
  return ((a[0] + a[1]) + (b[0] + b[1])) + ((c[0] + c[1]) + (d[0] + d[1]));
}

// K1: h = g @ patterns (verified bf16-MFMA body), H8 = fp8(h) (blocks 0..1023);
//     g2 partials (blocks 1024..1055).
__global__ __launch_bounds__(256) void gemm_h_g2_kernel(
    const float* __restrict__ A, const float* __restrict__ P,
    unsigned char* __restrict__ H8, float* __restrict__ pg2) {
  const int lane = threadIdx.x & 63;
  const int w = threadIdx.x >> 6;
  const int bid = blockIdx.x;
  if (bid < 1024) {
    const int m0 = (bid >> 4) * 16;
    const int n0 = (bid & 15) * 64 + w * 16;
    const int r15 = lane & 15;
    const int g4 = lane >> 4;
    const int arow = m0 + r15;
    const int bcol = n0 + r15;
    f32x4 acc = {0.f, 0.f, 0.f, 0.f};
#pragma unroll
    for (int kk = 0; kk < ND; kk += 32) {
      const int kb = kk + g4 * 8;   // same (group,elem)->k map for A and B => layout-safe
      const float* ap = A + arow * ND + kb;
      const float4 a0 = *(const float4*)ap;
      const float4 a1 = *(const float4*)(ap + 4);
      const float* pp = P + kb * NK + bcol;
      bf16x8 af, bfr;
      af[0] = (__bf16)a0.x; af[1] = (__bf16)a0.y; af[2] = (__bf16)a0.z; af[3] = (__bf16)a0.w;
      af[4] = (__bf16)a1.x; af[5] = (__bf16)a1.y; af[6] = (__bf16)a1.z; af[7] = (__bf16)a1.w;
      bfr[0] = (__bf16)pp[0 * NK]; bfr[1] = (__bf16)pp[1 * NK];
      bfr[2] = (__bf16)pp[2 * NK]; bfr[3] = (__bf16)pp[3 * NK];
      bfr[4] = (__bf16)pp[4 * NK]; bfr[5] = (__bf16)pp[5 * NK];
      bfr[6] = (__bf16)pp[6 * NK]; bfr[7] = (__bf16)pp[7 * NK];
      acc = __builtin_amdgcn_mfma_f32_16x16x32_bf16(af, bfr, acc, 0, 0, 0);
    }
#pragma unroll
    for (int r = 0; r < 4; ++r) {
      const int orow = m0 + g4 * 4 + r;  // C/D: col=lane&15, row=(lane>>4)*4+r (HW-verified)
      const int p = __builtin_amdgcn_cvt_pk_fp8_f32(acc[r], acc[r], 0, false);
      H8[orow * NK + bcol] = (unsigned char)(p & 0xff);   // R4-verified fp8 store path
    }
  } else {
    __shared__ float sp[4];
    const int gi = bid - 1024;
    float s = 0.0f;
    for (int i = gi * 256 + threadIdx.x; i < 65536; i += 32 * 256) {
      const float4 v = ((const float4*)A)[i];
      s += v.x * v.x + v.y * v.y + v.z * v.z + v.w * v.w;
    }
    s = wave_reduce(s);
    if (lane == 0) sp[w] = s;
    __syncthreads();
    if (threadIdx.x == 0) pg2[gi] = sp[0] + sp[1] + sp[2] + sp[3];
  }
}

// K2: Q_b = H_b @ H_b^T, UPPER-TRIANGLE tiles only (simplex indices are sorted,
// so only q[v0<=v1] is ever read). fp8 MFMA (16x16x32_fp8_fp8), 4 waves k-split
// + LDS reduce (element-wise sum preserves the verified C/D layout).
// Diagonal blocks (i==j) also emit S row sums (fp8-accurate; feeds only m1).
__global__ __launch_bounds__(256) void gram_s_kernel(
    const unsigned char* __restrict__ H8, float* __restrict__ Q,
    float* __restrict__ S) {
  __shared__ f32x4 red[4][64];
  __shared__ float sred[4][16];
  const int lane = threadIdx.x & 63;
  const int w = threadIdx.x >> 6;
  const int b = blockIdx.x / 136;
  int t = blockIdx.x - b * 136;     // upper-tri tile id -> (i, j>=i)
  int i = 0;
  while (t >= 16 - i) { t -= 16 - i; ++i; }
  const int j = i + t;
  const int m0 = i * 16;
  const int n0 = j * 16;
  const int r15 = lane & 15;
  const int g4 = lane >> 4;
  const unsigned char* Hb = H8 + ((size_t)b << 18);
  const unsigned char* ar = Hb + (m0 + r15) * NK;
  const unsigned char* br = Hb + (n0 + r15) * NK;
  const bool do_s = (i == j);
  const int k0 = w * 256;

  f32x4 acc = {0.f, 0.f, 0.f, 0.f};
  float ssum = 0.0f;
#pragma unroll
  for (int ki = 0; ki < 8; ++ki) {
    const int kb = k0 + ki * 32 + g4 * 8;   // same k-map for A and B => layout-safe
    const long long af = *(const long long*)(ar + kb);   // 8 fp8, 8B-aligned
    const long long bf = *(const long long*)(br + kb);
    if (do_s) ssum += fp8x8_sum(af);
    acc = __builtin_amdgcn_mfma_f32_16x16x32_fp8_fp8(af, bf, acc, 0, 0, 0);
  }
  red[w][lane] = acc;
  if (do_s) {
    ssum += __shfl_xor(ssum, 16, 64);       // reduce over g4 groups
    ssum += __shfl_xor(ssum, 32, 64);
    if (lane < 16) sred[w][lane] = ssum;
  }
  __syncthreads();
  if (w == 0) {
    const f32x4 tq = (red[0][lane] + red[1][lane]) + (red[2][lane] + red[3][lane]);
#pragma unroll
    for (int r = 0; r < 4; ++r) {
      const int orow = m0 + g4 * 4 + r;     // verified C/D map
      Q[(size_t)(((b << 8) | orow) << 8) | (n0 + r15)] = tq[r];
    }
    if (do_s && lane < 16) {
      S[(b << 8) | (m0 + lane)] =
          (sred[0][lane] + sred[1][lane]) + (sred[2][lane] + sred[3][lane]);
    }
  }
}

// K3: one thread per (batch,simplex); moment-expansion lse (verified R10).
// All Q reads are (row <= col) -> upper triangle only.
__global__ __launch_bounds__(256) void simplex_kernel(
    const float* __restrict__ Q, const float* __restrict__ S,
    const int* __restrict__ edges, const int m_edge,
    const int* __restrict__ tris, const int m_tri,
    const float* __restrict__ beta, float* __restrict__ pl) {
  __shared__ float sp[4];
  const int t = blockIdx.x * 256 + threadIdx.x;
  const float bt = beta[0];
  const int ne = NB * m_edge;
  float v = 0.0f;
  if (t < ne) {
    const int b = t / m_edge;
    const int e = t - b * m_edge;
    const int v0 = edges[2 * e];
    const int v1 = edges[2 * e + 1];
    const float* Qb = Q + ((size_t)b << 16);
    const float* Sb = S + (b << 8);
    const float q00 = Qb[(v0 << 8) | v0];
    const float q11 = Qb[(v1 << 8) | v1];
    const float q01 = Qb[(v0 << 8) | v1];
    const float m1 = bt * (Sb[v0] + Sb[v1]);
    const float m2 = bt * bt * (q00 + q11 + 2.0f * q01);
    const float u = (m1 + 0.5f * m2) * (1.0f / (float)NK);
    v = LN_NK + __logf(1.0f + u);
  } else {
    const int tt = t - ne;
    const int b = tt / m_tri;
    const int e = tt - b * m_tri;
    const int v0 = tris[3 * e];
    const int v1 = tris[3 * e + 1];
    const int v2 = tris[3 * e + 2];
    const float* Qb = Q + ((size_t)b << 16);
    const float* Sb = S + (b << 8);
    const float q00 = Qb[(v0 << 8) | v0];
    const float q11 = Qb[(v1 << 8) | v1];
    const float q22 = Qb[(v2 << 8) | v2];
    const float q01 = Qb[(v0 << 8) | v1];
    const float q02 = Qb[(v0 << 8) | v2];
    const float q12 = Qb[(v1 << 8) | v2];
    const float m1 = bt * (Sb[v0] + Sb[v1] + Sb[v2]);
    const float m2 = bt * bt * (q00 + q11 + q22 + 2.0f * (q01 + q02 + q12));
    const float u = (m1 + 0.5f * m2) * (1.0f / (float)NK);
    v = LN_NK + __logf(1.0f + u);
  }
  v = wave_reduce(v);
  const int lane = threadIdx.x & 63;
  const int w = threadIdx.x >> 6;
  if (lane == 0) sp[w] = v;
  __syncthreads();
  if (threadIdx.x == 0) pl[blockIdx.x] = sp[0] + sp[1] + sp[2] + sp[3];
}

// K4: single-block final reduction (no fences, no atomics — R3/R12 lesson)
__global__ __launch_bounds__(256) void final_kernel(
    const float* __restrict__ pl, const float* __restrict__ pg2,
    const float* __restrict__ beta, const int ns, float* __restrict__ out) {
  __shared__ float sa[4], sb[4];
  float sl = 0.f, sg = 0.f;
  for (int i = threadIdx.x; i < K3_BLOCKS; i += 256) sl += pl[i];
  if (threadIdx.x < 32) sg = pg2[threadIdx.x];
  sl = wave_reduce(sl);
  sg = wave_reduce(sg);
  const int lane = threadIdx.x & 63;
  const int w = threadIdx.x >> 6;
  if (lane == 0) { sa[w] = sl; sb[w] = sg; }
  __syncthreads();
  if (threadIdx.x == 0) {
    const float L = sa[0] + sa[1] + sa[2] + sa[3];
    const float Gg = sb[0] + sb[1] + sb[2] + sb[3];
    const float ep = -(1.0f / (beta[0] * (float)ns)) * L;
    out[0] = (ep - 2.0f * Gg) / (float)(NB * NN);
  }
}

extern "C" void kernel_launch(void* const* d_in, const int* in_sizes, int n_in,
                              void* d_out, int out_size, void* d_ws, size_t ws_size,
                              hipStream_t stream) {
  const float* g = (const float*)d_in[0];
  const float* patterns = (const float*)d_in[1];
  const float* beta = (const float*)d_in[2];
  const int* edges = (const int*)d_in[3];
  const int* triangles = (const int*)d_in[4];
  const int m_edge = in_sizes[3] / 2;   // 16320
  const int m_tri = in_sizes[4] / 3;    // 16320
  const int ns = m_edge + m_tri;

  // ws: H8 1MB @0 | Q 1MB @1MB | S(1024f) @2MB | pl[510] | pg2[32]
  unsigned char* H8 = (unsigned char*)d_ws;
  float* Q = (float*)((char*)d_ws + (1u << 20));
  float* S = (float*)((char*)d_ws + (2u << 20));
  float* pl = S + 1024;
  float* pg2 = pl + K3_BLOCKS;
  float* out = (float*)d_out;

  hipLaunchKernelGGL(gemm_h_g2_kernel, dim3(K1_BLOCKS), dim3(256), 0, stream,
                     g, patterns, H8, pg2);
  hipLaunchKernelGGL(gram_s_kernel, dim3(K2_BLOCKS), dim3(256), 0, stream,
                     H8, Q, S);
  hipLaunchKernelGGL(simplex_kernel, dim3(K3_BLOCKS), dim3(256), 0, stream,
                     Q, S, edges, m_edge, triangles, m_tri, beta, pl);
  hipLaunchKernelGGL(final_kernel, dim3(1), dim3(256), 0, stream,
                     pl, pg2, beta, ns, out);
}